// Round 1
// baseline (1874.616 us; speedup 1.0000x reference)
//
#include <hip/hip_runtime.h>
#include <hip/hip_bf16.h>

#define N_NODES 50000
#define N_EDGES 800000
#define N_GRAPHS 128
#define HID 128
#define NK 3
#define NL 4
#define NC 10
#define BN_EPS 1e-5f

// ---------------------------------------------------------------- degrees
__global__ void degrees_kernel(const int* __restrict__ row, const int* __restrict__ col,
                               int* __restrict__ degr, int* __restrict__ degc) {
    int e = blockIdx.x * blockDim.x + threadIdx.x;
    if (e >= N_EDGES) return;
    atomicAdd(&degr[row[e]], 1);
    atomicAdd(&degc[col[e]], 1);
}

// ------------------------------------------------- exclusive scan (1 block)
__global__ __launch_bounds__(1024) void scan_kernel(const int* __restrict__ degc,
                                                    int* __restrict__ csr_off,
                                                    int* __restrict__ cursor) {
    __shared__ int buf[1024];
    int tid = threadIdx.x;
    const int chunk = (N_NODES + 1023) / 1024;
    int begin = tid * chunk;
    int endi = begin + chunk; if (endi > N_NODES) endi = N_NODES;
    int s = 0;
    for (int i = begin; i < endi; ++i) s += degc[i];
    buf[tid] = s;
    __syncthreads();
    for (int d = 1; d < 1024; d <<= 1) {
        int v = (tid >= d) ? buf[tid - d] : 0;
        __syncthreads();
        buf[tid] += v;
        __syncthreads();
    }
    int running = buf[tid] - s;   // exclusive prefix for this chunk
    for (int i = begin; i < endi; ++i) {
        csr_off[i] = running;
        cursor[i] = running;
        running += degc[i];
    }
    if (tid == 1023) csr_off[N_NODES] = N_EDGES;
}

// --------------------------------------- counting-sort scatter + pseudo coords
__global__ void fill_csr_kernel(const int* __restrict__ row, const int* __restrict__ col,
                                const int* __restrict__ degr, const int* __restrict__ degc,
                                int* __restrict__ cursor, int* __restrict__ csr_eid,
                                float* __restrict__ pseudo) {
    int e = blockIdx.x * blockDim.x + threadIdx.x;
    if (e >= N_EDGES) return;
    int r = row[e], c = col[e];
    int pos = atomicAdd(&cursor[c], 1);
    csr_eid[pos] = e;
    pseudo[e * 2 + 0] = rsqrtf((float)degr[r] + 1.0f);
    pseudo[e * 2 + 1] = rsqrtf((float)degc[c] + 1.0f);
}

// ----------------------------------------------------- per-layer edge weights
__global__ void edge_w_kernel(const float* __restrict__ pseudo,
                              const float* __restrict__ pp_w, const float* __restrict__ pp_b,
                              const float* __restrict__ mu, const float* __restrict__ isig,
                              float* __restrict__ wE) {
    int e = blockIdx.x * blockDim.x + threadIdx.x;
    if (e >= N_EDGES) return;
    float p0 = pseudo[e * 2], p1 = pseudo[e * 2 + 1];
    float ps0 = tanhf(p0 * pp_w[0] + p1 * pp_w[1] + pp_b[0]);
    float ps1 = tanhf(p0 * pp_w[2] + p1 * pp_w[3] + pp_b[1]);
#pragma unroll
    for (int k = 0; k < NK; ++k) {
        float d0 = ps0 - mu[k * 2 + 0], d1 = ps1 - mu[k * 2 + 1];
        float s0 = isig[k * 2 + 0],     s1 = isig[k * 2 + 1];
        wE[e * 3 + k] = expf(-0.5f * (d0 * d0 * s0 * s0 + d1 * d1 * s1 * s1));
    }
}

// --------------------------------------------------------------- fp32 GEMM
// C[M x Nc] = A[M x Kd] @ W[Nc x Kd]^T (+ bias).  Kd multiple of 16.
#define TM 64
#define TN 64
#define TK 16
__global__ __launch_bounds__(256) void gemm_nt_kernel(const float* __restrict__ A,
                                                      const float* __restrict__ W,
                                                      const float* __restrict__ bias,
                                                      float* __restrict__ C,
                                                      int M, int Nc, int Kd) {
    __shared__ float As[TK][TM + 1];
    __shared__ float Ws[TK][TN + 1];
    int bm = blockIdx.x * TM;
    int bn = blockIdx.y * TN;
    int tid = threadIdx.x;
    int tm = (tid >> 4) << 2;   // 0..60
    int tn = (tid & 15) << 2;   // 0..60
    float acc[4][4] = {};
    for (int k0 = 0; k0 < Kd; k0 += TK) {
        {
            int r = tid >> 2;
            int kk = (tid & 3) << 2;
            float4 v = make_float4(0.f, 0.f, 0.f, 0.f);
            int gr = bm + r;
            if (gr < M) v = *(const float4*)(A + (size_t)gr * Kd + k0 + kk);
            As[kk + 0][r] = v.x; As[kk + 1][r] = v.y; As[kk + 2][r] = v.z; As[kk + 3][r] = v.w;
        }
        {
            int c = tid >> 2;
            int kk = (tid & 3) << 2;
            float4 v = make_float4(0.f, 0.f, 0.f, 0.f);
            int gc = bn + c;
            if (gc < Nc) v = *(const float4*)(W + (size_t)gc * Kd + k0 + kk);
            Ws[kk + 0][c] = v.x; Ws[kk + 1][c] = v.y; Ws[kk + 2][c] = v.z; Ws[kk + 3][c] = v.w;
        }
        __syncthreads();
#pragma unroll
        for (int kk = 0; kk < TK; ++kk) {
            float a0 = As[kk][tm + 0], a1 = As[kk][tm + 1], a2 = As[kk][tm + 2], a3 = As[kk][tm + 3];
            float b0 = Ws[kk][tn + 0], b1 = Ws[kk][tn + 1], b2 = Ws[kk][tn + 2], b3 = Ws[kk][tn + 3];
            acc[0][0] += a0 * b0; acc[0][1] += a0 * b1; acc[0][2] += a0 * b2; acc[0][3] += a0 * b3;
            acc[1][0] += a1 * b0; acc[1][1] += a1 * b1; acc[1][2] += a1 * b2; acc[1][3] += a1 * b3;
            acc[2][0] += a2 * b0; acc[2][1] += a2 * b1; acc[2][2] += a2 * b2; acc[2][3] += a2 * b3;
            acc[3][0] += a3 * b0; acc[3][1] += a3 * b1; acc[3][2] += a3 * b2; acc[3][3] += a3 * b3;
        }
        __syncthreads();
    }
#pragma unroll
    for (int i = 0; i < 4; ++i) {
        int gr = bm + tm + i;
        if (gr >= M) break;
#pragma unroll
        for (int j = 0; j < 4; ++j) {
            int gc = bn + tn + j;
            float v = acc[i][j];
            if (bias) v += bias[gc];
            C[(size_t)gr * Nc + gc] = v;
        }
    }
}

// --------------------------------------------------------- CSR aggregation
// one wave per destination node; t layout [N][3*HID] (k-interleaved)
__global__ __launch_bounds__(256) void aggregate_kernel(const int* __restrict__ csr_off,
                                                        const int* __restrict__ csr_eid,
                                                        const int* __restrict__ row,
                                                        const float* __restrict__ wE,
                                                        const float* __restrict__ t,
                                                        float* __restrict__ agg) {
    int wave = threadIdx.x >> 6;
    int lane = threadIdx.x & 63;
    int n = blockIdx.x * 4 + wave;
    if (n >= N_NODES) return;
    int beg = csr_off[n], end = csr_off[n + 1];
    float2 acc = make_float2(0.f, 0.f);
    for (int e = beg; e < end; ++e) {
        int eid = csr_eid[e];
        int r = row[eid];
        float w0 = wE[eid * 3 + 0], w1 = wE[eid * 3 + 1], w2 = wE[eid * 3 + 2];
        const float2* tp = (const float2*)(t + (size_t)r * (3 * HID));
        float2 a0 = tp[lane], a1 = tp[64 + lane], a2 = tp[128 + lane];
        acc.x += w0 * a0.x + w1 * a1.x + w2 * a2.x;
        acc.y += w0 * a0.y + w1 * a1.y + w2 * a2.y;
    }
    ((float2*)(agg + (size_t)n * HID))[lane] = acc;
}

// ----------------------------------------------------------------- BN stats
__global__ __launch_bounds__(256) void bn_stats_kernel(const float* __restrict__ agg,
                                                       float* __restrict__ bnsum) {
    __shared__ float ssum[256], ssq[256];
    int c = threadIdx.x & 127;
    int rh = threadIdx.x >> 7;   // 0/1
    int r0 = blockIdx.x * 128;
    int rend = r0 + 128; if (rend > N_NODES) rend = N_NODES;
    float s = 0.f, q = 0.f;
    for (int r = r0 + rh; r < rend; r += 2) {
        float v = agg[(size_t)r * HID + c];
        s += v; q += v * v;
    }
    ssum[threadIdx.x] = s; ssq[threadIdx.x] = q;
    __syncthreads();
    if (rh == 0) {
        atomicAdd(&bnsum[c],       ssum[c] + ssum[c + 128]);
        atomicAdd(&bnsum[128 + c], ssq[c]  + ssq[c + 128]);
    }
}

// ------------------------------------------- BN apply + ReLU + residual
__global__ void bn_apply_kernel(float* __restrict__ h, const float* __restrict__ agg,
                                const float* __restrict__ bnsum,
                                const float* __restrict__ gamma, const float* __restrict__ beta) {
    int idx = blockIdx.x * blockDim.x + threadIdx.x;
    if (idx >= N_NODES * HID) return;
    int c = idx & (HID - 1);
    const float invN = 1.0f / (float)N_NODES;
    float mean = bnsum[c] * invN;
    float var = bnsum[HID + c] * invN - mean * mean;
    float inv = rsqrtf(var + BN_EPS);
    float hn = (agg[idx] - mean) * inv * gamma[c] + beta[c];
    h[idx] += fmaxf(hn, 0.f);
}

// -------------------------------------------- fused readout + 3-layer MLP
__global__ __launch_bounds__(128) void readout_mlp_kernel(const float* __restrict__ h,
                                                          const int* __restrict__ batch,
                                                          const float* __restrict__ w0, const float* __restrict__ b0,
                                                          const float* __restrict__ w1, const float* __restrict__ b1,
                                                          const float* __restrict__ w2, const float* __restrict__ b2,
                                                          float* __restrict__ out) {
    __shared__ float hg[128];
    __shared__ float z0[64];
    __shared__ float z1[32];
    __shared__ int range[2];
    int g = blockIdx.x;
    int tid = threadIdx.x;
    if (tid == 0) {
        int lo = 0, hi = N_NODES;
        while (lo < hi) { int mid = (lo + hi) >> 1; if (batch[mid] < g) lo = mid + 1; else hi = mid; }
        range[0] = lo;
        hi = N_NODES;
        while (lo < hi) { int mid = (lo + hi) >> 1; if (batch[mid] < g + 1) lo = mid + 1; else hi = mid; }
        range[1] = lo;
    }
    __syncthreads();
    int lo = range[0], hi = range[1];
    float s = 0.f;
    for (int n = lo; n < hi; ++n) s += h[(size_t)n * HID + tid];
    int cnt = hi - lo; if (cnt < 1) cnt = 1;
    hg[tid] = s / (float)cnt;
    __syncthreads();
    if (tid < 64) {
        float a = b0[tid];
        for (int i = 0; i < 128; ++i) a += hg[i] * w0[tid * 128 + i];
        z0[tid] = fmaxf(a, 0.f);
    }
    __syncthreads();
    if (tid < 32) {
        float a = b1[tid];
        for (int i = 0; i < 64; ++i) a += z0[i] * w1[tid * 64 + i];
        z1[tid] = fmaxf(a, 0.f);
    }
    __syncthreads();
    if (tid < 10) {
        float a = b2[tid];
        for (int i = 0; i < 32; ++i) a += z1[i] * w2[tid * 32 + i];
        out[g * NC + tid] = a;
    }
}

// ----------------------------------------------------------------- launch
extern "C" void kernel_launch(void* const* d_in, const int* in_sizes, int n_in,
                              void* d_out, int out_size, void* d_ws, size_t ws_size,
                              hipStream_t stream) {
    const float* feature = (const float*)d_in[0];
    const int*   edge    = (const int*)d_in[1];
    const int*   row     = edge;
    const int*   col     = edge + N_EDGES;
    const int*   batch   = (const int*)d_in[2];
    const float* emb_w   = (const float*)d_in[3];
    const float* emb_b   = (const float*)d_in[4];
    const float* fc_w    = (const float*)d_in[5];
    const float* mu      = (const float*)d_in[6];
    const float* isig    = (const float*)d_in[7];
    const float* gamma   = (const float*)d_in[8];
    const float* beta    = (const float*)d_in[9];
    const float* pp_w    = (const float*)d_in[10];
    const float* pp_b    = (const float*)d_in[11];
    const float* mw0     = (const float*)d_in[12];
    const float* mb0     = (const float*)d_in[13];
    const float* mw1     = (const float*)d_in[14];
    const float* mb1     = (const float*)d_in[15];
    const float* mw2     = (const float*)d_in[16];
    const float* mb2     = (const float*)d_in[17];
    float* out = (float*)d_out;

    // workspace carve-up (256B aligned)
    char* ws = (char*)d_ws;
    size_t off = 0;
    auto carve = [&](size_t bytes) { size_t o = off; off = (off + bytes + 255) & ~(size_t)255; return o; };
    float* h      = (float*)(ws + carve((size_t)N_NODES * HID * 4));
    float* t      = (float*)(ws + carve((size_t)N_NODES * 3 * HID * 4));
    float* agg    = (float*)(ws + carve((size_t)N_NODES * HID * 4));
    float* pseudo = (float*)(ws + carve((size_t)N_EDGES * 2 * 4));
    float* wE     = (float*)(ws + carve((size_t)N_EDGES * 3 * 4));
    int* degr     = (int*)(ws + carve((size_t)N_NODES * 4));
    int* degc     = (int*)(ws + carve((size_t)N_NODES * 4));
    int* csr_off  = (int*)(ws + carve((size_t)(N_NODES + 1) * 4));
    int* cursor   = (int*)(ws + carve((size_t)N_NODES * 4));
    int* csr_eid  = (int*)(ws + carve((size_t)N_EDGES * 4));
    float* bnsum  = (float*)(ws + carve((size_t)2 * HID * 4));
    (void)ws_size; (void)in_sizes; (void)n_in; (void)out_size;

    hipMemsetAsync(degr, 0, (size_t)N_NODES * 4, stream);
    hipMemsetAsync(degc, 0, (size_t)N_NODES * 4, stream);

    degrees_kernel<<<(N_EDGES + 255) / 256, 256, 0, stream>>>(row, col, degr, degc);
    scan_kernel<<<1, 1024, 0, stream>>>(degc, csr_off, cursor);
    fill_csr_kernel<<<(N_EDGES + 255) / 256, 256, 0, stream>>>(row, col, degr, degc, cursor, csr_eid, pseudo);

    // h = feature @ emb_w^T + emb_b
    gemm_nt_kernel<<<dim3((N_NODES + TM - 1) / TM, HID / TN), 256, 0, stream>>>(
        feature, emb_w, emb_b, h, N_NODES, HID, HID);

    for (int l = 0; l < NL; ++l) {
        edge_w_kernel<<<(N_EDGES + 255) / 256, 256, 0, stream>>>(
            pseudo, pp_w + l * 4, pp_b + l * 2, mu + l * NK * 2, isig + l * NK * 2, wE);
        // t[n][k*H+j] = sum_i h[n][i] * fc_w[l][k*H+j][i]
        gemm_nt_kernel<<<dim3((N_NODES + TM - 1) / TM, (3 * HID) / TN), 256, 0, stream>>>(
            h, fc_w + (size_t)l * NK * HID * HID, nullptr, t, N_NODES, 3 * HID, HID);
        aggregate_kernel<<<(N_NODES + 3) / 4, 256, 0, stream>>>(csr_off, csr_eid, row, wE, t, agg);
        hipMemsetAsync(bnsum, 0, 2 * HID * 4, stream);
        bn_stats_kernel<<<(N_NODES + 127) / 128, 256, 0, stream>>>(agg, bnsum);
        bn_apply_kernel<<<(N_NODES * HID + 255) / 256, 256, 0, stream>>>(
            h, agg, bnsum, gamma + l * HID, beta + l * HID);
    }

    readout_mlp_kernel<<<N_GRAPHS, 128, 0, stream>>>(h, batch, mw0, mb0, mw1, mb1, mw2, mb2, out);
}

// Round 2
// 1184.173 us; speedup vs baseline: 1.5831x; 1.5831x over previous
//
#include <hip/hip_runtime.h>
#include <hip/hip_bf16.h>

#define N_NODES 50000
#define N_EDGES 800000
#define N_GRAPHS 128
#define HID 128
#define NK 3
#define NL 4
#define NC 10
#define BN_EPS 1e-5f

__device__ __forceinline__ float tanh_fast(float x) {
    float ax = fabsf(x);
    float t = __expf(-2.0f * ax);
    float r = (1.0f - t) / (1.0f + t);
    return copysignf(r, x);
}

// ---------------------------------------------------------------- degrees
__global__ void degrees_kernel(const int* __restrict__ row, const int* __restrict__ col,
                               int* __restrict__ degr, int* __restrict__ degc) {
    int e = blockIdx.x * blockDim.x + threadIdx.x;
    if (e >= N_EDGES) return;
    atomicAdd(&degr[row[e]], 1);
    atomicAdd(&degc[col[e]], 1);
}

// ------------------------------------------------- exclusive scan (1 block)
__global__ __launch_bounds__(1024) void scan_kernel(const int* __restrict__ degc,
                                                    int* __restrict__ csr_off,
                                                    int* __restrict__ cursor) {
    __shared__ int buf[1024];
    int tid = threadIdx.x;
    const int chunk = (N_NODES + 1023) / 1024;
    int begin = tid * chunk;
    int endi = begin + chunk; if (endi > N_NODES) endi = N_NODES;
    int s = 0;
    for (int i = begin; i < endi; ++i) s += degc[i];
    buf[tid] = s;
    __syncthreads();
    for (int d = 1; d < 1024; d <<= 1) {
        int v = (tid >= d) ? buf[tid - d] : 0;
        __syncthreads();
        buf[tid] += v;
        __syncthreads();
    }
    int running = buf[tid] - s;   // exclusive prefix for this chunk
    for (int i = begin; i < endi; ++i) {
        csr_off[i] = running;
        cursor[i] = running;
        running += degc[i];
    }
    if (tid == 1023) csr_off[N_NODES] = N_EDGES;
}

// ------------------------- counting-sort scatter: CSR-ordered row + pseudo
__global__ void fill_csr_kernel(const int* __restrict__ row, const int* __restrict__ col,
                                const int* __restrict__ degr, const int* __restrict__ degc,
                                int* __restrict__ cursor, int* __restrict__ row_s,
                                float2* __restrict__ pseudo_s) {
    int e = blockIdx.x * blockDim.x + threadIdx.x;
    if (e >= N_EDGES) return;
    int r = row[e], c = col[e];
    int pos = atomicAdd(&cursor[c], 1);
    row_s[pos] = r;
    pseudo_s[pos] = make_float2(rsqrtf((float)degr[r] + 1.0f), rsqrtf((float)degc[c] + 1.0f));
}

// ------------------------------------- per-layer edge weights (CSR order)
__global__ void edge_w_kernel(const float2* __restrict__ ps_in,
                              const float* __restrict__ pp_w, const float* __restrict__ pp_b,
                              const float* __restrict__ mu, const float* __restrict__ isig,
                              float4* __restrict__ wE) {
    int e = blockIdx.x * blockDim.x + threadIdx.x;
    if (e >= N_EDGES) return;
    float2 p = ps_in[e];
    float ps0 = tanh_fast(p.x * pp_w[0] + p.y * pp_w[1] + pp_b[0]);
    float ps1 = tanh_fast(p.x * pp_w[2] + p.y * pp_w[3] + pp_b[1]);
    float w[NK];
#pragma unroll
    for (int k = 0; k < NK; ++k) {
        float d0 = ps0 - mu[k * 2 + 0], d1 = ps1 - mu[k * 2 + 1];
        float s0 = isig[k * 2 + 0],     s1 = isig[k * 2 + 1];
        w[k] = __expf(-0.5f * (d0 * d0 * s0 * s0 + d1 * d1 * s1 * s1));
    }
    wE[e] = make_float4(w[0], w[1], w[2], 0.0f);
}

// ------------------- fc_w transpose: w2t[l][j][k*H+i] = fc_w[l][k*H+j][i]
__global__ void transpose_fc_kernel(const float* __restrict__ fc_w, float* __restrict__ w2t) {
    int idx = blockIdx.x * blockDim.x + threadIdx.x;
    if (idx >= NL * NK * HID * HID) return;
    int i = idx & (HID - 1);
    int j = (idx >> 7) & (HID - 1);
    int kl = idx >> 14;          // l*3 + k
    int k = kl % 3;
    int l = kl / 3;
    w2t[((size_t)(l * HID + j)) * (NK * HID) + k * HID + i] = fc_w[idx];
}

// --------------------------------------------------------------- fp32 GEMM
// C[M x 128] = A[M x Kd] @ W[128 x Kd]^T (+bias). Optional fused BN stats.
#define BM 64
#define BK 16
__global__ __launch_bounds__(256) void gemm_kernel(const float* __restrict__ A,
                                                   const float* __restrict__ W,
                                                   const float* __restrict__ bias,
                                                   float* __restrict__ C,
                                                   float* __restrict__ bnsum,
                                                   int M, int Kd) {
    __shared__ float As[BK][68];
    __shared__ float Ws[BK][132];
    __shared__ float bsum[HID], bsq[HID];
    int tid = threadIdx.x;
    if (bnsum && tid < HID) { bsum[tid] = 0.f; bsq[tid] = 0.f; }
    int bm = blockIdx.x * BM;
    int tx = tid & 15, ty = tid >> 4;
    float acc[4][8] = {};
    int ar = tid >> 2, ak = (tid & 3) << 2;
    int wc = tid >> 1, wk = (tid & 1) << 3;
    const float* Arow = A + (size_t)(bm + ar) * Kd + ak;
    bool avalid = (bm + ar) < M;
    const float* Wrow = W + (size_t)wc * Kd + wk;
    for (int k0 = 0; k0 < Kd; k0 += BK) {
        float4 av = avalid ? *(const float4*)(Arow + k0) : make_float4(0.f, 0.f, 0.f, 0.f);
        float4 w0 = *(const float4*)(Wrow + k0);
        float4 w1 = *(const float4*)(Wrow + k0 + 4);
        __syncthreads();
        As[ak + 0][ar] = av.x; As[ak + 1][ar] = av.y; As[ak + 2][ar] = av.z; As[ak + 3][ar] = av.w;
        Ws[wk + 0][wc] = w0.x; Ws[wk + 1][wc] = w0.y; Ws[wk + 2][wc] = w0.z; Ws[wk + 3][wc] = w0.w;
        Ws[wk + 4][wc] = w1.x; Ws[wk + 5][wc] = w1.y; Ws[wk + 6][wc] = w1.z; Ws[wk + 7][wc] = w1.w;
        __syncthreads();
#pragma unroll
        for (int kk = 0; kk < BK; ++kk) {
            float4 a  = *(const float4*)&As[kk][ty * 4];
            float4 b0 = *(const float4*)&Ws[kk][tx * 8];
            float4 b1 = *(const float4*)&Ws[kk][tx * 8 + 4];
            float aa[4] = {a.x, a.y, a.z, a.w};
            float bb[8] = {b0.x, b0.y, b0.z, b0.w, b1.x, b1.y, b1.z, b1.w};
#pragma unroll
            for (int i = 0; i < 4; ++i)
#pragma unroll
                for (int j = 0; j < 8; ++j)
                    acc[i][j] += aa[i] * bb[j];
        }
    }
    float bv[8];
#pragma unroll
    for (int j = 0; j < 8; ++j) bv[j] = bias ? bias[tx * 8 + j] : 0.f;
#pragma unroll
    for (int i = 0; i < 4; ++i) {
        int gr = bm + ty * 4 + i;
        if (gr < M) {
            float o[8];
#pragma unroll
            for (int j = 0; j < 8; ++j) o[j] = acc[i][j] + bv[j];
            *(float4*)(C + (size_t)gr * HID + tx * 8)     = make_float4(o[0], o[1], o[2], o[3]);
            *(float4*)(C + (size_t)gr * HID + tx * 8 + 4) = make_float4(o[4], o[5], o[6], o[7]);
        }
    }
    if (bnsum) {
        float s[8] = {}, q[8] = {};
#pragma unroll
        for (int i = 0; i < 4; ++i) {
            if (bm + ty * 4 + i < M) {
#pragma unroll
                for (int j = 0; j < 8; ++j) { float v = acc[i][j]; s[j] += v; q[j] += v * v; }
            }
        }
#pragma unroll
        for (int j = 0; j < 8; ++j) {
            s[j] += __shfl_xor(s[j], 16); s[j] += __shfl_xor(s[j], 32);
            q[j] += __shfl_xor(q[j], 16); q[j] += __shfl_xor(q[j], 32);
        }
        if ((tid & 63) < 16) {
            int cb = tx * 8;
#pragma unroll
            for (int j = 0; j < 8; ++j) {
                atomicAdd(&bsum[cb + j], s[j]);
                atomicAdd(&bsq[cb + j],  q[j]);
            }
        }
        __syncthreads();
        if (tid < HID) {
            atomicAdd(&bnsum[tid],       bsum[tid]);
            atomicAdd(&bnsum[HID + tid], bsq[tid]);
        }
    }
}

// --------------------------------- CSR aggregation in h-space (u = [N,3H])
__global__ __launch_bounds__(256) void aggregate_kernel(const int* __restrict__ csr_off,
                                                        const int* __restrict__ row_s,
                                                        const float4* __restrict__ wE,
                                                        const float2* __restrict__ h2,
                                                        float2* __restrict__ u2) {
    int wave = threadIdx.x >> 6;
    int lane = threadIdx.x & 63;
    int n = blockIdx.x * 4 + wave;
    if (n >= N_NODES) return;
    int beg = csr_off[n], end = csr_off[n + 1];
    float2 a0 = {0.f, 0.f}, a1 = {0.f, 0.f}, a2 = {0.f, 0.f};
    int r = 0; float4 w = make_float4(0.f, 0.f, 0.f, 0.f);
    if (beg < end) { r = row_s[beg]; w = wE[beg]; }
    for (int e = beg; e < end; ++e) {
        int rn = 0; float4 wn = make_float4(0.f, 0.f, 0.f, 0.f);
        if (e + 1 < end) { rn = row_s[e + 1]; wn = wE[e + 1]; }
        float2 hv = h2[(size_t)r * 64 + lane];
        a0.x += w.x * hv.x; a0.y += w.x * hv.y;
        a1.x += w.y * hv.x; a1.y += w.y * hv.y;
        a2.x += w.z * hv.x; a2.y += w.z * hv.y;
        r = rn; w = wn;
    }
    size_t b = (size_t)n * 192 + lane;
    u2[b] = a0; u2[b + 64] = a1; u2[b + 128] = a2;
}

// ------------------------------------------- BN apply + ReLU + residual
__global__ void bn_apply_kernel(float4* __restrict__ h4, const float4* __restrict__ agg4,
                                const float* __restrict__ bnsum,
                                const float* __restrict__ gamma, const float* __restrict__ beta) {
    int idx = blockIdx.x * blockDim.x + threadIdx.x;
    if (idx >= N_NODES * HID / 4) return;
    int c = (idx & 31) * 4;
    const float invN = 1.0f / (float)N_NODES;
    float4 a = agg4[idx];
    float4 hv = h4[idx];
    float av[4] = {a.x, a.y, a.z, a.w};
    float hh[4] = {hv.x, hv.y, hv.z, hv.w};
    float o[4];
#pragma unroll
    for (int j = 0; j < 4; ++j) {
        float mean = bnsum[c + j] * invN;
        float var = bnsum[HID + c + j] * invN - mean * mean;
        float hn = (av[j] - mean) * rsqrtf(var + BN_EPS) * gamma[c + j] + beta[c + j];
        o[j] = hh[j] + fmaxf(hn, 0.f);
    }
    h4[idx] = make_float4(o[0], o[1], o[2], o[3]);
}

// -------------------------------------------- fused readout + 3-layer MLP
__global__ __launch_bounds__(128) void readout_mlp_kernel(const float* __restrict__ h,
                                                          const int* __restrict__ batch,
                                                          const float* __restrict__ w0, const float* __restrict__ b0,
                                                          const float* __restrict__ w1, const float* __restrict__ b1,
                                                          const float* __restrict__ w2, const float* __restrict__ b2,
                                                          float* __restrict__ out) {
    __shared__ float hg[128];
    __shared__ float z0[64];
    __shared__ float z1[32];
    __shared__ int range[2];
    int g = blockIdx.x;
    int tid = threadIdx.x;
    if (tid == 0) {
        int lo = 0, hi = N_NODES;
        while (lo < hi) { int mid = (lo + hi) >> 1; if (batch[mid] < g) lo = mid + 1; else hi = mid; }
        range[0] = lo;
        hi = N_NODES;
        while (lo < hi) { int mid = (lo + hi) >> 1; if (batch[mid] < g + 1) lo = mid + 1; else hi = mid; }
        range[1] = lo;
    }
    __syncthreads();
    int lo = range[0], hi = range[1];
    float s0 = 0.f, s1 = 0.f, s2 = 0.f, s3 = 0.f;
    int n = lo;
    for (; n + 4 <= hi; n += 4) {
        s0 += h[(size_t)n * HID + tid];
        s1 += h[(size_t)(n + 1) * HID + tid];
        s2 += h[(size_t)(n + 2) * HID + tid];
        s3 += h[(size_t)(n + 3) * HID + tid];
    }
    for (; n < hi; ++n) s0 += h[(size_t)n * HID + tid];
    float s = (s0 + s1) + (s2 + s3);
    int cnt = hi - lo; if (cnt < 1) cnt = 1;
    hg[tid] = s / (float)cnt;
    __syncthreads();
    if (tid < 64) {
        float a = b0[tid];
        for (int i = 0; i < 128; ++i) a += hg[i] * w0[tid * 128 + i];
        z0[tid] = fmaxf(a, 0.f);
    }
    __syncthreads();
    if (tid < 32) {
        float a = b1[tid];
        for (int i = 0; i < 64; ++i) a += z0[i] * w1[tid * 64 + i];
        z1[tid] = fmaxf(a, 0.f);
    }
    __syncthreads();
    if (tid < 10) {
        float a = b2[tid];
        for (int i = 0; i < 32; ++i) a += z1[i] * w2[tid * 32 + i];
        out[g * NC + tid] = a;
    }
}

// ----------------------------------------------------------------- launch
extern "C" void kernel_launch(void* const* d_in, const int* in_sizes, int n_in,
                              void* d_out, int out_size, void* d_ws, size_t ws_size,
                              hipStream_t stream) {
    const float* feature = (const float*)d_in[0];
    const int*   edge    = (const int*)d_in[1];
    const int*   row     = edge;
    const int*   col     = edge + N_EDGES;
    const int*   batch   = (const int*)d_in[2];
    const float* emb_w   = (const float*)d_in[3];
    const float* emb_b   = (const float*)d_in[4];
    const float* fc_w    = (const float*)d_in[5];
    const float* mu      = (const float*)d_in[6];
    const float* isig    = (const float*)d_in[7];
    const float* gamma   = (const float*)d_in[8];
    const float* beta    = (const float*)d_in[9];
    const float* pp_w    = (const float*)d_in[10];
    const float* pp_b    = (const float*)d_in[11];
    const float* mw0     = (const float*)d_in[12];
    const float* mb0     = (const float*)d_in[13];
    const float* mw1     = (const float*)d_in[14];
    const float* mb1     = (const float*)d_in[15];
    const float* mw2     = (const float*)d_in[16];
    const float* mb2     = (const float*)d_in[17];
    float* out = (float*)d_out;

    // workspace carve-up (256B aligned)
    char* ws = (char*)d_ws;
    size_t off = 0;
    auto carve = [&](size_t bytes) { size_t o = off; off = (off + bytes + 255) & ~(size_t)255; return o; };
    float* h        = (float*)(ws + carve((size_t)N_NODES * HID * 4));
    float* u        = (float*)(ws + carve((size_t)N_NODES * NK * HID * 4));
    float* agg      = (float*)(ws + carve((size_t)N_NODES * HID * 4));
    float2* pseudo_s= (float2*)(ws + carve((size_t)N_EDGES * 2 * 4));
    float4* wE      = (float4*)(ws + carve((size_t)N_EDGES * 4 * 4));
    float* w2t      = (float*)(ws + carve((size_t)NL * HID * NK * HID * 4));
    int* degr       = (int*)(ws + carve((size_t)N_NODES * 4));
    int* degc       = (int*)(ws + carve((size_t)N_NODES * 4));
    int* csr_off    = (int*)(ws + carve((size_t)(N_NODES + 1) * 4));
    int* cursor     = (int*)(ws + carve((size_t)N_NODES * 4));
    int* row_s      = (int*)(ws + carve((size_t)N_EDGES * 4));
    float* bnsum    = (float*)(ws + carve((size_t)NL * 2 * HID * 4));
    (void)ws_size; (void)in_sizes; (void)n_in; (void)out_size;

    hipMemsetAsync(degr, 0, (size_t)N_NODES * 4, stream);
    hipMemsetAsync(degc, 0, (size_t)N_NODES * 4, stream);
    hipMemsetAsync(bnsum, 0, (size_t)NL * 2 * HID * 4, stream);

    degrees_kernel<<<(N_EDGES + 255) / 256, 256, 0, stream>>>(row, col, degr, degc);
    scan_kernel<<<1, 1024, 0, stream>>>(degc, csr_off, cursor);
    fill_csr_kernel<<<(N_EDGES + 255) / 256, 256, 0, stream>>>(row, col, degr, degc, cursor, row_s, pseudo_s);
    transpose_fc_kernel<<<(NL * NK * HID * HID + 255) / 256, 256, 0, stream>>>(fc_w, w2t);

    // h = feature @ emb_w^T + emb_b
    gemm_kernel<<<(N_NODES + BM - 1) / BM, 256, 0, stream>>>(
        feature, emb_w, emb_b, h, nullptr, N_NODES, HID);

    for (int l = 0; l < NL; ++l) {
        edge_w_kernel<<<(N_EDGES + 255) / 256, 256, 0, stream>>>(
            pseudo_s, pp_w + l * 4, pp_b + l * 2, mu + l * NK * 2, isig + l * NK * 2, wE);
        aggregate_kernel<<<(N_NODES + 3) / 4, 256, 0, stream>>>(
            csr_off, row_s, wE, (const float2*)h, (float2*)u);
        gemm_kernel<<<(N_NODES + BM - 1) / BM, 256, 0, stream>>>(
            u, w2t + (size_t)l * HID * NK * HID, nullptr, agg, bnsum + l * 2 * HID, N_NODES, NK * HID);
        bn_apply_kernel<<<(N_NODES * HID / 4 + 255) / 256, 256, 0, stream>>>(
            (float4*)h, (const float4*)agg, bnsum + l * 2 * HID, gamma + l * HID, beta + l * HID);
    }

    readout_mlp_kernel<<<N_GRAPHS, 128, 0, stream>>>(h, batch, mw0, mb0, mw1, mb1, mw2, mb2, out);
}

// Round 3
// 913.597 us; speedup vs baseline: 2.0519x; 1.2962x over previous
//
#include <hip/hip_runtime.h>
#include <hip/hip_bf16.h>

#define N_NODES 50000
#define N_EDGES 800000
#define N_GRAPHS 128
#define HID 128
#define NK 3
#define NL 4
#define NC 10
#define BN_EPS 1e-5f
#define SCAN_G ((N_NODES + 255) / 256)

typedef __attribute__((ext_vector_type(8))) short short8;
typedef __attribute__((ext_vector_type(4))) float floatx4;

__device__ __forceinline__ float tanh_fast(float x) {
    float ax = fabsf(x);
    float t = __expf(-2.0f * ax);
    float r = (1.0f - t) / (1.0f + t);
    return copysignf(r, x);
}

__device__ __forceinline__ unsigned short f2bf(float f) {
    unsigned u = __float_as_uint(f);
    unsigned r = (u + 0x7FFFu + ((u >> 16) & 1u)) >> 16;
    return (unsigned short)r;
}
__device__ __forceinline__ float bf2f(unsigned short s) {
    return __uint_as_float(((unsigned)s) << 16);
}

// ---------------------------------------------------------------- degrees
__global__ void degrees_kernel(const int* __restrict__ row, const int* __restrict__ col,
                               int* __restrict__ degr, int* __restrict__ degc) {
    int e = blockIdx.x * blockDim.x + threadIdx.x;
    if (e >= N_EDGES) return;
    atomicAdd(&degr[row[e]], 1);
    atomicAdd(&degc[col[e]], 1);
}

// ------------------------------------------------ hierarchical scan (3 kernels)
__global__ __launch_bounds__(256) void scan1_kernel(const int* __restrict__ degc,
                                                    int* __restrict__ csr_off,
                                                    int* __restrict__ blocksum) {
    __shared__ int buf[256];
    int tid = threadIdx.x;
    int i = blockIdx.x * 256 + tid;
    int v = (i < N_NODES) ? degc[i] : 0;
    buf[tid] = v;
    __syncthreads();
    for (int d = 1; d < 256; d <<= 1) {
        int t = (tid >= d) ? buf[tid - d] : 0;
        __syncthreads();
        buf[tid] += t;
        __syncthreads();
    }
    if (i < N_NODES) csr_off[i] = buf[tid] - v;
    if (tid == 255) blocksum[blockIdx.x] = buf[255];
}

__global__ __launch_bounds__(256) void scan2_kernel(int* __restrict__ blocksum) {
    __shared__ int buf[256];
    int tid = threadIdx.x;
    int v = (tid < SCAN_G) ? blocksum[tid] : 0;
    buf[tid] = v;
    __syncthreads();
    for (int d = 1; d < 256; d <<= 1) {
        int t = (tid >= d) ? buf[tid - d] : 0;
        __syncthreads();
        buf[tid] += t;
        __syncthreads();
    }
    if (tid < SCAN_G) blocksum[tid] = buf[tid] - v;   // exclusive, in place
}

__global__ __launch_bounds__(256) void scan3_kernel(const int* __restrict__ blocksum,
                                                    int* __restrict__ csr_off,
                                                    int* __restrict__ cursor) {
    int i = blockIdx.x * 256 + threadIdx.x;
    if (i < N_NODES) {
        int v = csr_off[i] + blocksum[blockIdx.x];
        csr_off[i] = v;
        cursor[i] = v;
    }
    if (i == 0) csr_off[N_NODES] = N_EDGES;
}

// ------------------------- counting-sort scatter: CSR-ordered row + pseudo
__global__ void fill_csr_kernel(const int* __restrict__ row, const int* __restrict__ col,
                                const int* __restrict__ degr, const int* __restrict__ degc,
                                int* __restrict__ cursor, int* __restrict__ row_s,
                                float2* __restrict__ pseudo_s) {
    int e = blockIdx.x * blockDim.x + threadIdx.x;
    if (e >= N_EDGES) return;
    int r = row[e], c = col[e];
    int pos = atomicAdd(&cursor[c], 1);
    row_s[pos] = r;
    pseudo_s[pos] = make_float2(rsqrtf((float)degr[r] + 1.0f), rsqrtf((float)degc[c] + 1.0f));
}

// ------------------------------------- per-layer edge weights (CSR order)
__global__ void edge_w_kernel(const float2* __restrict__ ps_in,
                              const float* __restrict__ pp_w, const float* __restrict__ pp_b,
                              const float* __restrict__ mu, const float* __restrict__ isig,
                              float4* __restrict__ wE) {
    int e = blockIdx.x * blockDim.x + threadIdx.x;
    if (e >= N_EDGES) return;
    float2 p = ps_in[e];
    float ps0 = tanh_fast(p.x * pp_w[0] + p.y * pp_w[1] + pp_b[0]);
    float ps1 = tanh_fast(p.x * pp_w[2] + p.y * pp_w[3] + pp_b[1]);
    float w[NK];
#pragma unroll
    for (int k = 0; k < NK; ++k) {
        float d0 = ps0 - mu[k * 2 + 0], d1 = ps1 - mu[k * 2 + 1];
        float s0 = isig[k * 2 + 0],     s1 = isig[k * 2 + 1];
        w[k] = __expf(-0.5f * (d0 * d0 * s0 * s0 + d1 * d1 * s1 * s1));
    }
    wE[e] = make_float4(w[0], w[1], w[2], 0.0f);
}

// ------------------------------- element-wise fp32 -> (hi,lo) bf16 split
__global__ void split_kernel(const float* __restrict__ src, unsigned short* __restrict__ hi,
                             unsigned short* __restrict__ lo, int n) {
    int i = blockIdx.x * blockDim.x + threadIdx.x;
    if (i >= n) return;
    float f = src[i];
    unsigned short h = f2bf(f);
    hi[i] = h;
    lo[i] = f2bf(f - bf2f(h));
}

// ---------- fc_w transpose + split: w2t[l][j][k*H+i] = fc_w[l][k*H+j][i]
__global__ void transpose_split_fc_kernel(const float* __restrict__ fc_w,
                                          unsigned short* __restrict__ w2t_hi,
                                          unsigned short* __restrict__ w2t_lo) {
    int idx = blockIdx.x * blockDim.x + threadIdx.x;
    if (idx >= NL * NK * HID * HID) return;
    int i = idx & (HID - 1);
    int j = (idx >> 7) & (HID - 1);
    int kl = idx >> 14;          // l*3 + k
    int k = kl % 3;
    int l = kl / 3;
    float f = fc_w[idx];
    unsigned short h = f2bf(f);
    size_t dst = ((size_t)(l * HID + j)) * (NK * HID) + k * HID + i;
    w2t_hi[dst] = h;
    w2t_lo[dst] = f2bf(f - bf2f(h));
}

// -------------------------------------------------- split-bf16 MFMA GEMM
// C[M x 128] = A[M x Kd] @ W[128 x Kd]^T (+bias). Optional fused BN stats.
// A,W given as (hi,lo) bf16 pairs; acc = Ah*Wh + Ah*Wl + Al*Wh in fp32.
__global__ __launch_bounds__(256) void gemm_mfma_kernel(
        const unsigned short* __restrict__ A_hi, const unsigned short* __restrict__ A_lo,
        const unsigned short* __restrict__ W_hi, const unsigned short* __restrict__ W_lo,
        const float* __restrict__ bias, float* __restrict__ C,
        float* __restrict__ bnsum, int M, int Kd) {
    __shared__ unsigned short lds[4 * 128 * 40];   // Ah | Al | Bh | Bl, stride 40
    __shared__ float bsum[HID], bsq[HID];
    unsigned short* sAh = lds;
    unsigned short* sAl = lds + 5120;
    unsigned short* sBh = lds + 10240;
    unsigned short* sBl = lds + 15360;
    int tid = threadIdx.x;
    if (bnsum && tid < HID) { bsum[tid] = 0.f; bsq[tid] = 0.f; }
    int bm = blockIdx.x * 128;
    int wave = tid >> 6, lane = tid & 63;
    int ln = lane & 15, quad = lane >> 4;
    int wy = wave >> 1, wx = wave & 1;
    int srow = tid >> 2, scol = (tid & 3) << 3;
    floatx4 acc[4][4] = {};
    const short8 zv = {0, 0, 0, 0, 0, 0, 0, 0};

    for (int k0 = 0; k0 < Kd; k0 += 32) {
        __syncthreads();
#pragma unroll
        for (int rep = 0; rep < 2; ++rep) {
            int r = srow + rep * 64;
            size_t goW = (size_t)r * Kd + k0 + scol;
            short8 ah = zv, al = zv;
            if (bm + r < M) {
                size_t goA = (size_t)(bm + r) * Kd + k0 + scol;
                ah = *(const short8*)(A_hi + goA);
                al = *(const short8*)(A_lo + goA);
            }
            *(short8*)&sAh[r * 40 + scol] = ah;
            *(short8*)&sAl[r * 40 + scol] = al;
            *(short8*)&sBh[r * 40 + scol] = *(const short8*)(W_hi + goW);
            *(short8*)&sBl[r * 40 + scol] = *(const short8*)(W_lo + goW);
        }
        __syncthreads();
        short8 ah[4], al[4], bh[4], bl[4];
        int kq = quad * 8;
#pragma unroll
        for (int i = 0; i < 4; ++i) {
            int ra = wy * 64 + i * 16 + ln;
            int rb = wx * 64 + i * 16 + ln;
            ah[i] = *(const short8*)&sAh[ra * 40 + kq];
            al[i] = *(const short8*)&sAl[ra * 40 + kq];
            bh[i] = *(const short8*)&sBh[rb * 40 + kq];
            bl[i] = *(const short8*)&sBl[rb * 40 + kq];
        }
#pragma unroll
        for (int i = 0; i < 4; ++i)
#pragma unroll
            for (int j = 0; j < 4; ++j) {
                acc[i][j] = __builtin_amdgcn_mfma_f32_16x16x32_bf16(ah[i], bh[j], acc[i][j], 0, 0, 0);
                acc[i][j] = __builtin_amdgcn_mfma_f32_16x16x32_bf16(ah[i], bl[j], acc[i][j], 0, 0, 0);
                acc[i][j] = __builtin_amdgcn_mfma_f32_16x16x32_bf16(al[i], bh[j], acc[i][j], 0, 0, 0);
            }
    }

    // epilogue: C/D layout col = lane&15, row = quad*4 + reg
#pragma unroll
    for (int j = 0; j < 4; ++j) {
        int gc = wx * 64 + j * 16 + ln;
        float bv = bias ? bias[gc] : 0.f;
#pragma unroll
        for (int i = 0; i < 4; ++i) {
#pragma unroll
            for (int r = 0; r < 4; ++r) {
                int gr = bm + wy * 64 + i * 16 + quad * 4 + r;
                if (gr < M) C[(size_t)gr * HID + gc] = acc[i][j][r] + bv;
            }
        }
    }
    if (bnsum) {
#pragma unroll
        for (int j = 0; j < 4; ++j) {
            float s = 0.f, q = 0.f;
#pragma unroll
            for (int i = 0; i < 4; ++i)
#pragma unroll
                for (int r = 0; r < 4; ++r) { float v = acc[i][j][r]; s += v; q += v * v; }
            s += __shfl_xor(s, 16); s += __shfl_xor(s, 32);
            q += __shfl_xor(q, 16); q += __shfl_xor(q, 32);
            if (quad == 0) {
                atomicAdd(&bsum[wx * 64 + j * 16 + ln], s);
                atomicAdd(&bsq[wx * 64 + j * 16 + ln], q);
            }
        }
        __syncthreads();
        if (tid < HID) {
            atomicAdd(&bnsum[tid],       bsum[tid]);
            atomicAdd(&bnsum[HID + tid], bsq[tid]);
        }
    }
}

// ----------- CSR aggregation in h-space; emits u as (hi,lo) bf16 [N][384]
__global__ __launch_bounds__(256) void aggregate_kernel(const int* __restrict__ csr_off,
                                                        const int* __restrict__ row_s,
                                                        const float4* __restrict__ wE,
                                                        const float2* __restrict__ h2,
                                                        unsigned short* __restrict__ u_hi,
                                                        unsigned short* __restrict__ u_lo) {
    int wave = threadIdx.x >> 6;
    int lane = threadIdx.x & 63;
    int n = blockIdx.x * 4 + wave;
    if (n >= N_NODES) return;
    int beg = csr_off[n], end = csr_off[n + 1];
    float2 a0 = {0.f, 0.f}, a1 = {0.f, 0.f}, a2 = {0.f, 0.f};
    int r = 0; float4 w = make_float4(0.f, 0.f, 0.f, 0.f);
    if (beg < end) { r = row_s[beg]; w = wE[beg]; }
    for (int e = beg; e < end; ++e) {
        int rn = 0; float4 wn = make_float4(0.f, 0.f, 0.f, 0.f);
        if (e + 1 < end) { rn = row_s[e + 1]; wn = wE[e + 1]; }
        float2 hv = h2[(size_t)r * 64 + lane];
        a0.x += w.x * hv.x; a0.y += w.x * hv.y;
        a1.x += w.y * hv.x; a1.y += w.y * hv.y;
        a2.x += w.z * hv.x; a2.y += w.z * hv.y;
        r = rn; w = wn;
    }
    size_t base = (size_t)n * 384 + lane * 2;
    float2 vals[3] = {a0, a1, a2};
#pragma unroll
    for (int k = 0; k < 3; ++k) {
        unsigned short hx = f2bf(vals[k].x), hy = f2bf(vals[k].y);
        ushort2 hv, lv;
        hv.x = hx; hv.y = hy;
        lv.x = f2bf(vals[k].x - bf2f(hx));
        lv.y = f2bf(vals[k].y - bf2f(hy));
        *(ushort2*)(u_hi + base + k * 128) = hv;
        *(ushort2*)(u_lo + base + k * 128) = lv;
    }
}

// ------------------------------------------- BN apply + ReLU + residual
__global__ void bn_apply_kernel(float4* __restrict__ h4, const float4* __restrict__ agg4,
                                const float* __restrict__ bnsum,
                                const float* __restrict__ gamma, const float* __restrict__ beta) {
    int idx = blockIdx.x * blockDim.x + threadIdx.x;
    if (idx >= N_NODES * HID / 4) return;
    int c = (idx & 31) * 4;
    const float invN = 1.0f / (float)N_NODES;
    float4 a = agg4[idx];
    float4 hv = h4[idx];
    float av[4] = {a.x, a.y, a.z, a.w};
    float hh[4] = {hv.x, hv.y, hv.z, hv.w};
    float o[4];
#pragma unroll
    for (int j = 0; j < 4; ++j) {
        float mean = bnsum[c + j] * invN;
        float var = bnsum[HID + c + j] * invN - mean * mean;
        float hn = (av[j] - mean) * rsqrtf(var + BN_EPS) * gamma[c + j] + beta[c + j];
        o[j] = hh[j] + fmaxf(hn, 0.f);
    }
    h4[idx] = make_float4(o[0], o[1], o[2], o[3]);
}

// -------------------------------------------- fused readout + 3-layer MLP
__global__ __launch_bounds__(128) void readout_mlp_kernel(const float* __restrict__ h,
                                                          const int* __restrict__ batch,
                                                          const float* __restrict__ w0, const float* __restrict__ b0,
                                                          const float* __restrict__ w1, const float* __restrict__ b1,
                                                          const float* __restrict__ w2, const float* __restrict__ b2,
                                                          float* __restrict__ out) {
    __shared__ float hg[128];
    __shared__ float z0[64];
    __shared__ float z1[32];
    __shared__ int range[2];
    int g = blockIdx.x;
    int tid = threadIdx.x;
    if (tid == 0) {
        int lo = 0, hi = N_NODES;
        while (lo < hi) { int mid = (lo + hi) >> 1; if (batch[mid] < g) lo = mid + 1; else hi = mid; }
        range[0] = lo;
        hi = N_NODES;
        while (lo < hi) { int mid = (lo + hi) >> 1; if (batch[mid] < g + 1) lo = mid + 1; else hi = mid; }
        range[1] = lo;
    }
    __syncthreads();
    int lo = range[0], hi = range[1];
    float s0 = 0.f, s1 = 0.f, s2 = 0.f, s3 = 0.f;
    int n = lo;
    for (; n + 4 <= hi; n += 4) {
        s0 += h[(size_t)n * HID + tid];
        s1 += h[(size_t)(n + 1) * HID + tid];
        s2 += h[(size_t)(n + 2) * HID + tid];
        s3 += h[(size_t)(n + 3) * HID + tid];
    }
    for (; n < hi; ++n) s0 += h[(size_t)n * HID + tid];
    float s = (s0 + s1) + (s2 + s3);
    int cnt = hi - lo; if (cnt < 1) cnt = 1;
    hg[tid] = s / (float)cnt;
    __syncthreads();
    if (tid < 64) {
        float a = b0[tid];
        for (int i = 0; i < 128; ++i) a += hg[i] * w0[tid * 128 + i];
        z0[tid] = fmaxf(a, 0.f);
    }
    __syncthreads();
    if (tid < 32) {
        float a = b1[tid];
        for (int i = 0; i < 64; ++i) a += z0[i] * w1[tid * 64 + i];
        z1[tid] = fmaxf(a, 0.f);
    }
    __syncthreads();
    if (tid < 10) {
        float a = b2[tid];
        for (int i = 0; i < 32; ++i) a += z1[i] * w2[tid * 32 + i];
        out[g * NC + tid] = a;
    }
}

// ----------------------------------------------------------------- launch
extern "C" void kernel_launch(void* const* d_in, const int* in_sizes, int n_in,
                              void* d_out, int out_size, void* d_ws, size_t ws_size,
                              hipStream_t stream) {
    const float* feature = (const float*)d_in[0];
    const int*   edge    = (const int*)d_in[1];
    const int*   row     = edge;
    const int*   col     = edge + N_EDGES;
    const int*   batch   = (const int*)d_in[2];
    const float* emb_w   = (const float*)d_in[3];
    const float* emb_b   = (const float*)d_in[4];
    const float* fc_w    = (const float*)d_in[5];
    const float* mu      = (const float*)d_in[6];
    const float* isig    = (const float*)d_in[7];
    const float* gamma   = (const float*)d_in[8];
    const float* beta    = (const float*)d_in[9];
    const float* pp_w    = (const float*)d_in[10];
    const float* pp_b    = (const float*)d_in[11];
    const float* mw0     = (const float*)d_in[12];
    const float* mb0     = (const float*)d_in[13];
    const float* mw1     = (const float*)d_in[14];
    const float* mb1     = (const float*)d_in[15];
    const float* mw2     = (const float*)d_in[16];
    const float* mb2     = (const float*)d_in[17];
    float* out = (float*)d_out;

    // workspace carve-up (256B aligned)
    char* ws = (char*)d_ws;
    size_t off = 0;
    auto carve = [&](size_t bytes) { size_t o = off; off = (off + bytes + 255) & ~(size_t)255; return o; };
    float* h        = (float*)(ws + carve((size_t)N_NODES * HID * 4));
    unsigned short* u_hi = (unsigned short*)(ws + carve((size_t)N_NODES * NK * HID * 2));
    unsigned short* u_lo = (unsigned short*)(ws + carve((size_t)N_NODES * NK * HID * 2));
    float* agg      = (float*)(ws + carve((size_t)N_NODES * HID * 4));
    float2* pseudo_s= (float2*)(ws + carve((size_t)N_EDGES * 2 * 4));
    float4* wE      = (float4*)(ws + carve((size_t)N_EDGES * 4 * 4));
    unsigned short* w2t_hi = (unsigned short*)(ws + carve((size_t)NL * HID * NK * HID * 2));
    unsigned short* w2t_lo = (unsigned short*)(ws + carve((size_t)NL * HID * NK * HID * 2));
    unsigned short* f_hi   = (unsigned short*)(ws + carve((size_t)N_NODES * HID * 2));
    unsigned short* f_lo   = (unsigned short*)(ws + carve((size_t)N_NODES * HID * 2));
    unsigned short* e_hi   = (unsigned short*)(ws + carve((size_t)HID * HID * 2));
    unsigned short* e_lo   = (unsigned short*)(ws + carve((size_t)HID * HID * 2));
    int* degr       = (int*)(ws + carve((size_t)N_NODES * 4));
    int* degc       = (int*)(ws + carve((size_t)N_NODES * 4));
    int* csr_off    = (int*)(ws + carve((size_t)(N_NODES + 1) * 4));
    int* cursor     = (int*)(ws + carve((size_t)N_NODES * 4));
    int* row_s      = (int*)(ws + carve((size_t)N_EDGES * 4));
    int* blocksum   = (int*)(ws + carve((size_t)SCAN_G * 4));
    float* bnsum    = (float*)(ws + carve((size_t)NL * 2 * HID * 4));
    (void)ws_size; (void)in_sizes; (void)n_in; (void)out_size;

    hipMemsetAsync(degr, 0, (size_t)N_NODES * 4, stream);
    hipMemsetAsync(degc, 0, (size_t)N_NODES * 4, stream);
    hipMemsetAsync(bnsum, 0, (size_t)NL * 2 * HID * 4, stream);

    degrees_kernel<<<(N_EDGES + 255) / 256, 256, 0, stream>>>(row, col, degr, degc);
    scan1_kernel<<<SCAN_G, 256, 0, stream>>>(degc, csr_off, blocksum);
    scan2_kernel<<<1, 256, 0, stream>>>(blocksum);
    scan3_kernel<<<SCAN_G, 256, 0, stream>>>(blocksum, csr_off, cursor);
    fill_csr_kernel<<<(N_EDGES + 255) / 256, 256, 0, stream>>>(row, col, degr, degc, cursor, row_s, pseudo_s);

    split_kernel<<<(N_NODES * HID + 255) / 256, 256, 0, stream>>>(feature, f_hi, f_lo, N_NODES * HID);
    split_kernel<<<(HID * HID + 255) / 256, 256, 0, stream>>>(emb_w, e_hi, e_lo, HID * HID);
    transpose_split_fc_kernel<<<(NL * NK * HID * HID + 255) / 256, 256, 0, stream>>>(fc_w, w2t_hi, w2t_lo);

    // h = feature @ emb_w^T + emb_b
    gemm_mfma_kernel<<<(N_NODES + 127) / 128, 256, 0, stream>>>(
        f_hi, f_lo, e_hi, e_lo, emb_b, h, nullptr, N_NODES, HID);

    for (int l = 0; l < NL; ++l) {
        edge_w_kernel<<<(N_EDGES + 255) / 256, 256, 0, stream>>>(
            pseudo_s, pp_w + l * 4, pp_b + l * 2, mu + l * NK * 2, isig + l * NK * 2, wE);
        aggregate_kernel<<<(N_NODES + 3) / 4, 256, 0, stream>>>(
            csr_off, row_s, wE, (const float2*)h, u_hi, u_lo);
        gemm_mfma_kernel<<<(N_NODES + 127) / 128, 256, 0, stream>>>(
            u_hi, u_lo, w2t_hi + (size_t)l * HID * NK * HID, w2t_lo + (size_t)l * HID * NK * HID,
            nullptr, agg, bnsum + l * 2 * HID, N_NODES, NK * HID);
        bn_apply_kernel<<<(N_NODES * HID / 4 + 255) / 256, 256, 0, stream>>>(
            (float4*)h, (const float4*)agg, bnsum + l * 2 * HID, gamma + l * HID, beta + l * HID);
    }

    readout_mlp_kernel<<<N_GRAPHS, 128, 0, stream>>>(h, batch, mw0, mb0, mw1, mb1, mw2, mb2, out);
}

// Round 4
// 782.186 us; speedup vs baseline: 2.3966x; 1.1680x over previous
//
#include <hip/hip_runtime.h>
#include <hip/hip_bf16.h>

#define N_NODES 50000
#define N_EDGES 800000
#define N_GRAPHS 128
#define HID 128
#define NK 3
#define NL 4
#define NC 10
#define BN_EPS 1e-5f
#define SCAN_G ((N_NODES + 255) / 256)

typedef __attribute__((ext_vector_type(8))) short short8;
typedef __attribute__((ext_vector_type(4))) float floatx4;

__device__ __forceinline__ float tanh_fast(float x) {
    float ax = fabsf(x);
    float t = __expf(-2.0f * ax);
    float r = (1.0f - t) / (1.0f + t);
    return copysignf(r, x);
}

__device__ __forceinline__ unsigned short f2bf(float f) {
    unsigned u = __float_as_uint(f);
    unsigned r = (u + 0x7FFFu + ((u >> 16) & 1u)) >> 16;
    return (unsigned short)r;
}
__device__ __forceinline__ float bf2f(unsigned short s) {
    return __uint_as_float(((unsigned)s) << 16);
}

// ---------------------------------------------------------------- degrees
__global__ void degrees_kernel(const int* __restrict__ row, const int* __restrict__ col,
                               int* __restrict__ degr, int* __restrict__ degc) {
    int e = blockIdx.x * blockDim.x + threadIdx.x;
    if (e >= N_EDGES) return;
    atomicAdd(&degr[row[e]], 1);
    atomicAdd(&degc[col[e]], 1);
}

// ------------------------------------------------ hierarchical scan (3 kernels)
__global__ __launch_bounds__(256) void scan1_kernel(const int* __restrict__ degc,
                                                    int* __restrict__ csr_off,
                                                    int* __restrict__ blocksum) {
    __shared__ int buf[256];
    int tid = threadIdx.x;
    int i = blockIdx.x * 256 + tid;
    int v = (i < N_NODES) ? degc[i] : 0;
    buf[tid] = v;
    __syncthreads();
    for (int d = 1; d < 256; d <<= 1) {
        int t = (tid >= d) ? buf[tid - d] : 0;
        __syncthreads();
        buf[tid] += t;
        __syncthreads();
    }
    if (i < N_NODES) csr_off[i] = buf[tid] - v;
    if (tid == 255) blocksum[blockIdx.x] = buf[255];
}

__global__ __launch_bounds__(256) void scan2_kernel(int* __restrict__ blocksum) {
    __shared__ int buf[256];
    int tid = threadIdx.x;
    int v = (tid < SCAN_G) ? blocksum[tid] : 0;
    buf[tid] = v;
    __syncthreads();
    for (int d = 1; d < 256; d <<= 1) {
        int t = (tid >= d) ? buf[tid - d] : 0;
        __syncthreads();
        buf[tid] += t;
        __syncthreads();
    }
    if (tid < SCAN_G) blocksum[tid] = buf[tid] - v;   // exclusive, in place
}

__global__ __launch_bounds__(256) void scan3_kernel(const int* __restrict__ blocksum,
                                                    int* __restrict__ csr_off,
                                                    int* __restrict__ cursor) {
    int i = blockIdx.x * 256 + threadIdx.x;
    if (i < N_NODES) {
        int v = csr_off[i] + blocksum[blockIdx.x];
        csr_off[i] = v;
        cursor[i] = v;
    }
    if (i == 0) csr_off[N_NODES] = N_EDGES;
}

// ------------------------- counting-sort scatter: CSR-ordered row + pseudo
__global__ void fill_csr_kernel(const int* __restrict__ row, const int* __restrict__ col,
                                const int* __restrict__ degr, const int* __restrict__ degc,
                                int* __restrict__ cursor, int* __restrict__ row_s,
                                float2* __restrict__ pseudo_s) {
    int e = blockIdx.x * blockDim.x + threadIdx.x;
    if (e >= N_EDGES) return;
    int r = row[e], c = col[e];
    int pos = atomicAdd(&cursor[c], 1);
    row_s[pos] = r;
    pseudo_s[pos] = make_float2(rsqrtf((float)degr[r] + 1.0f), rsqrtf((float)degc[c] + 1.0f));
}

// -------------------- per-edge weights for ALL layers in one pass
__global__ void edge_w_all_kernel(const float2* __restrict__ ps_in,
                                  const float* __restrict__ pp_w, const float* __restrict__ pp_b,
                                  const float* __restrict__ mu, const float* __restrict__ isig,
                                  float4* __restrict__ wE) {
    int e = blockIdx.x * blockDim.x + threadIdx.x;
    if (e >= N_EDGES) return;
    float2 p = ps_in[e];
#pragma unroll
    for (int l = 0; l < NL; ++l) {
        float ps0 = tanh_fast(p.x * pp_w[l * 4 + 0] + p.y * pp_w[l * 4 + 1] + pp_b[l * 2 + 0]);
        float ps1 = tanh_fast(p.x * pp_w[l * 4 + 2] + p.y * pp_w[l * 4 + 3] + pp_b[l * 2 + 1]);
        float w[NK];
#pragma unroll
        for (int k = 0; k < NK; ++k) {
            float d0 = ps0 - mu[l * 6 + k * 2 + 0], d1 = ps1 - mu[l * 6 + k * 2 + 1];
            float s0 = isig[l * 6 + k * 2 + 0],     s1 = isig[l * 6 + k * 2 + 1];
            w[k] = __expf(-0.5f * (d0 * d0 * s0 * s0 + d1 * d1 * s1 * s1));
        }
        wE[(size_t)l * N_EDGES + e] = make_float4(w[0], w[1], w[2], 0.0f);
    }
}

// ------------------------------- element-wise fp32 -> (hi,lo) bf16 split
__global__ void split_kernel(const float* __restrict__ src, unsigned short* __restrict__ hi,
                             unsigned short* __restrict__ lo, int n) {
    int i = blockIdx.x * blockDim.x + threadIdx.x;
    if (i >= n) return;
    float f = src[i];
    unsigned short h = f2bf(f);
    hi[i] = h;
    lo[i] = f2bf(f - bf2f(h));
}

// ---------- fc_w transpose + split: w2t[l][j][k*H+i] = fc_w[l][k*H+j][i]
__global__ void transpose_split_fc_kernel(const float* __restrict__ fc_w,
                                          unsigned short* __restrict__ w2t_hi,
                                          unsigned short* __restrict__ w2t_lo) {
    int idx = blockIdx.x * blockDim.x + threadIdx.x;
    if (idx >= NL * NK * HID * HID) return;
    int i = idx & (HID - 1);
    int j = (idx >> 7) & (HID - 1);
    int kl = idx >> 14;          // l*3 + k
    int k = kl % 3;
    int l = kl / 3;
    float f = fc_w[idx];
    unsigned short h = f2bf(f);
    size_t dst = ((size_t)(l * HID + j)) * (NK * HID) + k * HID + i;
    w2t_hi[dst] = h;
    w2t_lo[dst] = f2bf(f - bf2f(h));
}

// -------------------------------------------------- split-bf16 MFMA GEMM
// C[M x 128] = A[M x Kd] @ W[128 x Kd]^T (+bias). Optional fused BN stats.
// acc = Ah*Wh + Ah*Wl + Al*Wh in fp32. Global->reg prefetch pipelined.
__global__ __launch_bounds__(256) void gemm_mfma_kernel(
        const unsigned short* __restrict__ A_hi, const unsigned short* __restrict__ A_lo,
        const unsigned short* __restrict__ W_hi, const unsigned short* __restrict__ W_lo,
        const float* __restrict__ bias, float* __restrict__ C,
        float* __restrict__ bnsum, int M, int Kd) {
    __shared__ unsigned short lds[4 * 128 * 40];   // Ah | Al | Bh | Bl, stride 40
    __shared__ float bsum[HID], bsq[HID];
    unsigned short* sAh = lds;
    unsigned short* sAl = lds + 5120;
    unsigned short* sBh = lds + 10240;
    unsigned short* sBl = lds + 15360;
    int tid = threadIdx.x;
    if (bnsum && tid < HID) { bsum[tid] = 0.f; bsq[tid] = 0.f; }
    int bm = blockIdx.x * 128;
    int wave = tid >> 6, lane = tid & 63;
    int ln = lane & 15, quad = lane >> 4;
    int wy = wave >> 1, wx = wave & 1;
    int srow = tid >> 2, scol = (tid & 3) << 3;
    floatx4 acc[4][4] = {};
    const short8 zv = {0, 0, 0, 0, 0, 0, 0, 0};

    short8 pAh[2], pAl[2], pBh[2], pBl[2];
    bool av0 = (bm + srow) < M, av1 = (bm + srow + 64) < M;
    const size_t aoff0 = (size_t)(bm + srow) * Kd + scol;
    const size_t aoff1 = (size_t)(bm + srow + 64) * Kd + scol;
    const size_t woff0 = (size_t)srow * Kd + scol;
    const size_t woff1 = (size_t)(srow + 64) * Kd + scol;

#define LOAD_TILE(K0)                                                          \
    do {                                                                       \
        pBh[0] = *(const short8*)(W_hi + woff0 + (K0));                        \
        pBl[0] = *(const short8*)(W_lo + woff0 + (K0));                        \
        pBh[1] = *(const short8*)(W_hi + woff1 + (K0));                        \
        pBl[1] = *(const short8*)(W_lo + woff1 + (K0));                        \
        pAh[0] = av0 ? *(const short8*)(A_hi + aoff0 + (K0)) : zv;             \
        pAl[0] = av0 ? *(const short8*)(A_lo + aoff0 + (K0)) : zv;             \
        pAh[1] = av1 ? *(const short8*)(A_hi + aoff1 + (K0)) : zv;             \
        pAl[1] = av1 ? *(const short8*)(A_lo + aoff1 + (K0)) : zv;             \
    } while (0)

    LOAD_TILE(0);
    for (int k0 = 0; k0 < Kd; k0 += 32) {
        __syncthreads();
#pragma unroll
        for (int rep = 0; rep < 2; ++rep) {
            int r = srow + rep * 64;
            *(short8*)&sAh[r * 40 + scol] = pAh[rep];
            *(short8*)&sAl[r * 40 + scol] = pAl[rep];
            *(short8*)&sBh[r * 40 + scol] = pBh[rep];
            *(short8*)&sBl[r * 40 + scol] = pBl[rep];
        }
        __syncthreads();
        if (k0 + 32 < Kd) LOAD_TILE(k0 + 32);   // overlaps with MFMA below
        short8 ah[4], al[4], bh[4], bl[4];
        int kq = quad * 8;
#pragma unroll
        for (int i = 0; i < 4; ++i) {
            int ra = wy * 64 + i * 16 + ln;
            int rb = wx * 64 + i * 16 + ln;
            ah[i] = *(const short8*)&sAh[ra * 40 + kq];
            al[i] = *(const short8*)&sAl[ra * 40 + kq];
            bh[i] = *(const short8*)&sBh[rb * 40 + kq];
            bl[i] = *(const short8*)&sBl[rb * 40 + kq];
        }
#pragma unroll
        for (int i = 0; i < 4; ++i)
#pragma unroll
            for (int j = 0; j < 4; ++j) {
                acc[i][j] = __builtin_amdgcn_mfma_f32_16x16x32_bf16(ah[i], bh[j], acc[i][j], 0, 0, 0);
                acc[i][j] = __builtin_amdgcn_mfma_f32_16x16x32_bf16(ah[i], bl[j], acc[i][j], 0, 0, 0);
                acc[i][j] = __builtin_amdgcn_mfma_f32_16x16x32_bf16(al[i], bh[j], acc[i][j], 0, 0, 0);
            }
    }
#undef LOAD_TILE

    // epilogue: C/D layout col = lane&15, row = quad*4 + reg
#pragma unroll
    for (int j = 0; j < 4; ++j) {
        int gc = wx * 64 + j * 16 + ln;
        float bv = bias ? bias[gc] : 0.f;
#pragma unroll
        for (int i = 0; i < 4; ++i) {
#pragma unroll
            for (int r = 0; r < 4; ++r) {
                int gr = bm + wy * 64 + i * 16 + quad * 4 + r;
                if (gr < M) C[(size_t)gr * HID + gc] = acc[i][j][r] + bv;
            }
        }
    }
    if (bnsum) {
#pragma unroll
        for (int j = 0; j < 4; ++j) {
            float s = 0.f, q = 0.f;
#pragma unroll
            for (int i = 0; i < 4; ++i)
#pragma unroll
                for (int r = 0; r < 4; ++r) { float v = acc[i][j][r]; s += v; q += v * v; }
            s += __shfl_xor(s, 16); s += __shfl_xor(s, 32);
            q += __shfl_xor(q, 16); q += __shfl_xor(q, 32);
            if (quad == 0) {
                atomicAdd(&bsum[wx * 64 + j * 16 + ln], s);
                atomicAdd(&bsq[wx * 64 + j * 16 + ln], q);
            }
        }
        __syncthreads();
        if (tid < HID) {
            atomicAdd(&bnsum[tid],       bsum[tid]);
            atomicAdd(&bnsum[HID + tid], bsq[tid]);
        }
    }
}

// ----------- CSR aggregation in h-space; emits u as (hi,lo) bf16 [N][384]
// edge loop unrolled x4 for memory-level parallelism
__global__ __launch_bounds__(256) void aggregate_kernel(const int* __restrict__ csr_off,
                                                        const int* __restrict__ row_s,
                                                        const float4* __restrict__ wE,
                                                        const float2* __restrict__ h2,
                                                        unsigned short* __restrict__ u_hi,
                                                        unsigned short* __restrict__ u_lo) {
    int wave = threadIdx.x >> 6;
    int lane = threadIdx.x & 63;
    int n = blockIdx.x * 4 + wave;
    if (n >= N_NODES) return;
    int beg = csr_off[n], end = csr_off[n + 1];
    float2 a0 = {0.f, 0.f}, a1 = {0.f, 0.f}, a2 = {0.f, 0.f};
    for (int e = beg; e < end; e += 4) {
        int r0 = row_s[e];
        float4 w0 = wE[e];
        int r1 = 0, r2 = 0, r3 = 0;
        float4 w1 = {0.f, 0.f, 0.f, 0.f}, w2 = w1, w3 = w1;
        if (e + 1 < end) { r1 = row_s[e + 1]; w1 = wE[e + 1]; }
        if (e + 2 < end) { r2 = row_s[e + 2]; w2 = wE[e + 2]; }
        if (e + 3 < end) { r3 = row_s[e + 3]; w3 = wE[e + 3]; }
        float2 h0 = h2[(size_t)r0 * 64 + lane];
        float2 h1 = h2[(size_t)r1 * 64 + lane];
        float2 hv2 = h2[(size_t)r2 * 64 + lane];
        float2 hv3 = h2[(size_t)r3 * 64 + lane];
        a0.x += w0.x * h0.x + w1.x * h1.x + w2.x * hv2.x + w3.x * hv3.x;
        a0.y += w0.x * h0.y + w1.x * h1.y + w2.x * hv2.y + w3.x * hv3.y;
        a1.x += w0.y * h0.x + w1.y * h1.x + w2.y * hv2.x + w3.y * hv3.x;
        a1.y += w0.y * h0.y + w1.y * h1.y + w2.y * hv2.y + w3.y * hv3.y;
        a2.x += w0.z * h0.x + w1.z * h1.x + w2.z * hv2.x + w3.z * hv3.x;
        a2.y += w0.z * h0.y + w1.z * h1.y + w2.z * hv2.y + w3.z * hv3.y;
    }
    size_t base = (size_t)n * 384 + lane * 2;
    float2 vals[3] = {a0, a1, a2};
#pragma unroll
    for (int k = 0; k < 3; ++k) {
        unsigned short hx = f2bf(vals[k].x), hy = f2bf(vals[k].y);
        ushort2 hv, lv;
        hv.x = hx; hv.y = hy;
        lv.x = f2bf(vals[k].x - bf2f(hx));
        lv.y = f2bf(vals[k].y - bf2f(hy));
        *(ushort2*)(u_hi + base + k * 128) = hv;
        *(ushort2*)(u_lo + base + k * 128) = lv;
    }
}

// ------------------------------------------- BN apply + ReLU + residual
__global__ void bn_apply_kernel(float4* __restrict__ h4, const float4* __restrict__ agg4,
                                const float* __restrict__ bnsum,
                                const float* __restrict__ gamma, const float* __restrict__ beta) {
    int idx = blockIdx.x * blockDim.x + threadIdx.x;
    if (idx >= N_NODES * HID / 4) return;
    int c = (idx & 31) * 4;
    const float invN = 1.0f / (float)N_NODES;
    float4 a = agg4[idx];
    float4 hv = h4[idx];
    float av[4] = {a.x, a.y, a.z, a.w};
    float hh[4] = {hv.x, hv.y, hv.z, hv.w};
    float o[4];
#pragma unroll
    for (int j = 0; j < 4; ++j) {
        float mean = bnsum[c + j] * invN;
        float var = bnsum[HID + c + j] * invN - mean * mean;
        float hn = (av[j] - mean) * rsqrtf(var + BN_EPS) * gamma[c + j] + beta[c + j];
        o[j] = hh[j] + fmaxf(hn, 0.f);
    }
    h4[idx] = make_float4(o[0], o[1], o[2], o[3]);
}

// -------------------------------------------- fused readout + 3-layer MLP
__global__ __launch_bounds__(128) void readout_mlp_kernel(const float* __restrict__ h,
                                                          const int* __restrict__ batch,
                                                          const float* __restrict__ w0, const float* __restrict__ b0,
                                                          const float* __restrict__ w1, const float* __restrict__ b1,
                                                          const float* __restrict__ w2, const float* __restrict__ b2,
                                                          float* __restrict__ out) {
    __shared__ float hg[128];
    __shared__ float z0[64];
    __shared__ float z1[32];
    __shared__ int range[2];
    int g = blockIdx.x;
    int tid = threadIdx.x;
    if (tid == 0) {
        int lo = 0, hi = N_NODES;
        while (lo < hi) { int mid = (lo + hi) >> 1; if (batch[mid] < g) lo = mid + 1; else hi = mid; }
        range[0] = lo;
        hi = N_NODES;
        while (lo < hi) { int mid = (lo + hi) >> 1; if (batch[mid] < g + 1) lo = mid + 1; else hi = mid; }
        range[1] = lo;
    }
    __syncthreads();
    int lo = range[0], hi = range[1];
    float s0 = 0.f, s1 = 0.f, s2 = 0.f, s3 = 0.f;
    int n = lo;
    for (; n + 4 <= hi; n += 4) {
        s0 += h[(size_t)n * HID + tid];
        s1 += h[(size_t)(n + 1) * HID + tid];
        s2 += h[(size_t)(n + 2) * HID + tid];
        s3 += h[(size_t)(n + 3) * HID + tid];
    }
    for (; n < hi; ++n) s0 += h[(size_t)n * HID + tid];
    float s = (s0 + s1) + (s2 + s3);
    int cnt = hi - lo; if (cnt < 1) cnt = 1;
    hg[tid] = s / (float)cnt;
    __syncthreads();
    if (tid < 64) {
        float a = b0[tid];
        for (int i = 0; i < 128; ++i) a += hg[i] * w0[tid * 128 + i];
        z0[tid] = fmaxf(a, 0.f);
    }
    __syncthreads();
    if (tid < 32) {
        float a = b1[tid];
        for (int i = 0; i < 64; ++i) a += z0[i] * w1[tid * 64 + i];
        z1[tid] = fmaxf(a, 0.f);
    }
    __syncthreads();
    if (tid < 10) {
        float a = b2[tid];
        for (int i = 0; i < 32; ++i) a += z1[i] * w2[tid * 32 + i];
        out[g * NC + tid] = a;
    }
}

// ----------------------------------------------------------------- launch
extern "C" void kernel_launch(void* const* d_in, const int* in_sizes, int n_in,
                              void* d_out, int out_size, void* d_ws, size_t ws_size,
                              hipStream_t stream) {
    const float* feature = (const float*)d_in[0];
    const int*   edge    = (const int*)d_in[1];
    const int*   row     = edge;
    const int*   col     = edge + N_EDGES;
    const int*   batch   = (const int*)d_in[2];
    const float* emb_w   = (const float*)d_in[3];
    const float* emb_b   = (const float*)d_in[4];
    const float* fc_w    = (const float*)d_in[5];
    const float* mu      = (const float*)d_in[6];
    const float* isig    = (const float*)d_in[7];
    const float* gamma   = (const float*)d_in[8];
    const float* beta    = (const float*)d_in[9];
    const float* pp_w    = (const float*)d_in[10];
    const float* pp_b    = (const float*)d_in[11];
    const float* mw0     = (const float*)d_in[12];
    const float* mb0     = (const float*)d_in[13];
    const float* mw1     = (const float*)d_in[14];
    const float* mb1     = (const float*)d_in[15];
    const float* mw2     = (const float*)d_in[16];
    const float* mb2     = (const float*)d_in[17];
    float* out = (float*)d_out;

    // workspace carve-up (256B aligned)
    char* ws = (char*)d_ws;
    size_t off = 0;
    auto carve = [&](size_t bytes) { size_t o = off; off = (off + bytes + 255) & ~(size_t)255; return o; };
    float* h        = (float*)(ws + carve((size_t)N_NODES * HID * 4));
    unsigned short* u_hi = (unsigned short*)(ws + carve((size_t)N_NODES * NK * HID * 2));
    unsigned short* u_lo = (unsigned short*)(ws + carve((size_t)N_NODES * NK * HID * 2));
    float* agg      = (float*)(ws + carve((size_t)N_NODES * HID * 4));
    float2* pseudo_s= (float2*)(ws + carve((size_t)N_EDGES * 2 * 4));
    float4* wE      = (float4*)(ws + carve((size_t)NL * N_EDGES * 4 * 4));
    unsigned short* w2t_hi = (unsigned short*)(ws + carve((size_t)NL * HID * NK * HID * 2));
    unsigned short* w2t_lo = (unsigned short*)(ws + carve((size_t)NL * HID * NK * HID * 2));
    unsigned short* f_hi   = (unsigned short*)(ws + carve((size_t)N_NODES * HID * 2));
    unsigned short* f_lo   = (unsigned short*)(ws + carve((size_t)N_NODES * HID * 2));
    unsigned short* e_hi   = (unsigned short*)(ws + carve((size_t)HID * HID * 2));
    unsigned short* e_lo   = (unsigned short*)(ws + carve((size_t)HID * HID * 2));
    int* degr       = (int*)(ws + carve((size_t)N_NODES * 4));
    int* degc       = (int*)(ws + carve((size_t)N_NODES * 4));
    int* csr_off    = (int*)(ws + carve((size_t)(N_NODES + 1) * 4));
    int* cursor     = (int*)(ws + carve((size_t)N_NODES * 4));
    int* row_s      = (int*)(ws + carve((size_t)N_EDGES * 4));
    int* blocksum   = (int*)(ws + carve((size_t)SCAN_G * 4));
    float* bnsum    = (float*)(ws + carve((size_t)NL * 2 * HID * 4));
    (void)ws_size; (void)in_sizes; (void)n_in; (void)out_size;

    hipMemsetAsync(degr, 0, (size_t)N_NODES * 4, stream);
    hipMemsetAsync(degc, 0, (size_t)N_NODES * 4, stream);
    hipMemsetAsync(bnsum, 0, (size_t)NL * 2 * HID * 4, stream);

    degrees_kernel<<<(N_EDGES + 255) / 256, 256, 0, stream>>>(row, col, degr, degc);
    scan1_kernel<<<SCAN_G, 256, 0, stream>>>(degc, csr_off, blocksum);
    scan2_kernel<<<1, 256, 0, stream>>>(blocksum);
    scan3_kernel<<<SCAN_G, 256, 0, stream>>>(blocksum, csr_off, cursor);
    fill_csr_kernel<<<(N_EDGES + 255) / 256, 256, 0, stream>>>(row, col, degr, degc, cursor, row_s, pseudo_s);
    edge_w_all_kernel<<<(N_EDGES + 255) / 256, 256, 0, stream>>>(pseudo_s, pp_w, pp_b, mu, isig, wE);

    split_kernel<<<(N_NODES * HID + 255) / 256, 256, 0, stream>>>(feature, f_hi, f_lo, N_NODES * HID);
    split_kernel<<<(HID * HID + 255) / 256, 256, 0, stream>>>(emb_w, e_hi, e_lo, HID * HID);
    transpose_split_fc_kernel<<<(NL * NK * HID * HID + 255) / 256, 256, 0, stream>>>(fc_w, w2t_hi, w2t_lo);

    // h = feature @ emb_w^T + emb_b
    gemm_mfma_kernel<<<(N_NODES + 127) / 128, 256, 0, stream>>>(
        f_hi, f_lo, e_hi, e_lo, emb_b, h, nullptr, N_NODES, HID);

    for (int l = 0; l < NL; ++l) {
        aggregate_kernel<<<(N_NODES + 3) / 4, 256, 0, stream>>>(
            csr_off, row_s, wE + (size_t)l * N_EDGES, (const float2*)h, u_hi, u_lo);
        gemm_mfma_kernel<<<(N_NODES + 127) / 128, 256, 0, stream>>>(
            u_hi, u_lo, w2t_hi + (size_t)l * HID * NK * HID, w2t_lo + (size_t)l * HID * NK * HID,
            nullptr, agg, bnsum + l * 2 * HID, N_NODES, NK * HID);
        bn_apply_kernel<<<(N_NODES * HID / 4 + 255) / 256, 256, 0, stream>>>(
            (float4*)h, (const float4*)agg, bnsum + l * 2 * HID, gamma + l * HID, beta + l * HID);
    }

    readout_mlp_kernel<<<N_GRAPHS, 128, 0, stream>>>(h, batch, mw0, mb0, mw1, mb1, mw2, mb2, out);
}